// Round 2
// baseline (254.378 us; speedup 1.0000x reference)
//
#include <hip/hip_runtime.h>

// Problem constants (reference: B=64, T=512, D=1024, U=128)
#define TT 512
#define DD 1024
#define UU 128
#define MM 32768            // B*T rows

typedef short short8 __attribute__((ext_vector_type(8)));   // 8 bf16 (MFMA A/B frag)
typedef float f32x4 __attribute__((ext_vector_type(4)));    // MFMA C/D frag

// fp32 -> bf16 round-to-nearest-even
__device__ __forceinline__ unsigned short f2bf(float f) {
    union { float f; unsigned u; } v; v.f = f;
    unsigned u = v.u;
    return (unsigned short)((u + 0x7fffu + ((u >> 16) & 1u)) >> 16);
}

// ---------------------------------------------------------------------------
// Kernel 0: W[k][n] fp32 (1024x128) -> ws bf16, transposed+chunked:
// wt[kc*8192 + n*64 + k'] = bf16(W[kc*64+k'][n]).  (unchanged from R1, verified)
// ---------------------------------------------------------------------------
__global__ __launch_bounds__(256) void wprep_kernel(const float* __restrict__ w,
                                                    unsigned short* __restrict__ wt) {
    int tg = blockIdx.x * 256 + threadIdx.x;   // 0..16383
    int kg = tg & 7;
    int n  = (tg >> 3) & 127;
    int kc = tg >> 10;
    union { unsigned short s[8]; uint4 v; } o;
#pragma unroll
    for (int j = 0; j < 8; ++j) {
        int k = kc * 64 + kg * 8 + j;
        o.s[j] = f2bf(w[k * 128 + n]);
    }
    *(uint4*)(wt + tg * 8) = o.v;
}

// ---------------------------------------------------------------------------
// Kernel 1: LDS-free, barrier-free GEMM + epilogue.
// Each wave: independent 16(M) x 64(N) tile, full K=1024 in 16 chunks of 64.
// A frags loaded directly from global x (fp32->bf16 in regs, prefetch +1 chunk).
// B frags loaded directly from wt (L1/L2-resident, 256 KiB total).
// Block = 4 waves: (mt in {0,1}) x (nh in {0,1}); nh-pair shares A rows -> L1 hit.
// ---------------------------------------------------------------------------
__global__ __launch_bounds__(256, 4) void crf_energy_kernel(
    const float* __restrict__ x,               // [32768, 1024]
    const int* __restrict__ mask,              // [32768]
    const unsigned short* __restrict__ wt,     // ws: bf16 Wt chunks
    const float* __restrict__ bias,            // [128]
    const float* __restrict__ lb,              // [128]
    const float* __restrict__ rb,              // [128]
    float* __restrict__ out)                   // [32768, 128]
{
    const int tid  = threadIdx.x;
    const int wave = tid >> 6;
    const int lane = tid & 63;
    const int q    = lane >> 4;                // 0..3
    const int r    = lane & 15;                // 0..15

    const int mt   = wave >> 1;                // row half within block
    const int nh   = wave & 1;                 // col half
    const int row0 = blockIdx.x * 32 + mt * 16;   // 1024 blocks * 32 rows

    // Per-lane A source row; within a row, lane reads floats [ks*32 + q*8, +8)
    const float* __restrict__ xrow = x + (size_t)(row0 + r) * DD;
    // Per-lane B base: row n = nh*64 + nt*16 + r of Wt chunk; +nt*1024, +ks*32, lane takes q*8
    const unsigned short* __restrict__ wbase = wt + (size_t)(nh * 64 + r) * 64 + q * 8;

    f32x4 acc[4];
#pragma unroll
    for (int nt = 0; nt < 4; ++nt) acc[nt] = (f32x4){0.f, 0.f, 0.f, 0.f};

    // ---- prefetch A chunk 0 (raw fp32): per ks two float4 (8 floats -> 8 bf16)
    float4 araw[2][2];
#pragma unroll
    for (int ks = 0; ks < 2; ++ks) {
        const float* p = xrow + ks * 32 + q * 8;
        araw[ks][0] = *(const float4*)(p);
        araw[ks][1] = *(const float4*)(p + 4);
    }

#pragma unroll 2
    for (int kc = 0; kc < 16; ++kc) {
        // ---- issue A prefetch for next chunk first (HBM latency cover)
        const int kcn = (kc < 15) ? kc + 1 : kc;   // clamp: no divergence, always valid
        float4 anxt[2][2];
#pragma unroll
        for (int ks = 0; ks < 2; ++ks) {
            const float* p = xrow + kcn * 64 + ks * 32 + q * 8;
            anxt[ks][0] = *(const float4*)(p);
            anxt[ks][1] = *(const float4*)(p + 4);
        }

        // ---- convert current A chunk to bf16 frags
        short8 afrag[2];
#pragma unroll
        for (int ks = 0; ks < 2; ++ks) {
            union { unsigned short s[8]; short8 v; } pk;
            pk.s[0] = f2bf(araw[ks][0].x); pk.s[1] = f2bf(araw[ks][0].y);
            pk.s[2] = f2bf(araw[ks][0].z); pk.s[3] = f2bf(araw[ks][0].w);
            pk.s[4] = f2bf(araw[ks][1].x); pk.s[5] = f2bf(araw[ks][1].y);
            pk.s[6] = f2bf(araw[ks][1].z); pk.s[7] = f2bf(araw[ks][1].w);
            afrag[ks] = pk.v;
        }

        // ---- B frags + MFMA, per ks (keeps only 4 b-frags live)
        const unsigned short* wkc = wbase + (size_t)kc * 8192;
#pragma unroll
        for (int ks = 0; ks < 2; ++ks) {
            short8 b[4];
#pragma unroll
            for (int nt = 0; nt < 4; ++nt)
                b[nt] = *(const short8*)(wkc + nt * 1024 + ks * 32);
#pragma unroll
            for (int nt = 0; nt < 4; ++nt)
                acc[nt] = __builtin_amdgcn_mfma_f32_16x16x32_bf16(
                    afrag[ks], b[nt], acc[nt], 0, 0, 0);
        }

        // rotate prefetch buffers
#pragma unroll
        for (int ks = 0; ks < 2; ++ks) {
            araw[ks][0] = anxt[ks][0];
            araw[ks][1] = anxt[ks][1];
        }
    }

    // ---- epilogue: bias + boundary masks.  C/D: col=lane&15 (N), row=q*4+reg (M).
#pragma unroll
    for (int nt = 0; nt < 4; ++nt) {
        const int n = nh * 64 + nt * 16 + r;
        const float bi  = bias[n];
        const float lbn = lb[n];
        const float rbn = rb[n];
#pragma unroll
        for (int reg = 0; reg < 4; ++reg) {
            const int m = row0 + q * 4 + reg;
            const int t = m & (TT - 1);
            const int cur  = mask[m];
            const int prev = (t != 0)      ? mask[m - 1] : 0;
            const int nxt  = (t != TT - 1) ? mask[m + 1] : 0;
            float e = acc[nt][reg] + bi;
            if (cur > prev) e += lbn;    // start_mask
            if (nxt > cur)  e += rbn;    // end_mask
            out[(size_t)m * UU + n] = e;
        }
    }
}

extern "C" void kernel_launch(void* const* d_in, const int* in_sizes, int n_in,
                              void* d_out, int out_size, void* d_ws, size_t ws_size,
                              hipStream_t stream) {
    const float* x    = (const float*)d_in[0];
    const int*   mask = (const int*)d_in[1];
    const float* w    = (const float*)d_in[2];
    const float* bias = (const float*)d_in[3];
    const float* lb   = (const float*)d_in[4];
    const float* rb   = (const float*)d_in[5];
    float* out = (float*)d_out;
    unsigned short* wt = (unsigned short*)d_ws;   // 256 KiB bf16 Wt

    wprep_kernel<<<64, 256, 0, stream>>>(w, wt);
    // 1024 blocks * 4 waves = 4096 waves = 16 waves/CU
    crf_energy_kernel<<<1024, 256, 0, stream>>>(x, mask, wt, bias, lb, rb, out);
}